// Round 3
// baseline (57.917 us; speedup 1.0000x reference)
//
#include <hip/hip_runtime.h>

// R3: barrier-free fused conv+MLP.
//   build_weights: fold conv into Weff^T, transpose W2/W3, all bf16 padded, in ws.
//   fused: per-wave streaming GEMM1 (A: global->reg prefetch, B: global L1/L2),
//          h1/h2 in LDS (per-wave rows only -> NO __syncthreads anywhere),
//          GEMM2/GEMM3 with B direct from ws.

typedef __attribute__((ext_vector_type(8))) short bf16x8;
typedef __attribute__((ext_vector_type(4))) float f32x4;

#define KP1 832     // GEMM1 K padded (784 -> 13*64)
#define NP  112     // hidden N padded (100 -> 7*16)
#define K2P 128     // GEMM2/3 K padded (100 -> 128)
#define BM  128
#define NT  256

#define W2T_OFF (NP * KP1)              // 93184
#define W3T_OFF (W2T_OFF + NP * K2P)    // 107520
#define WS_USHORTS (W3T_OFF + 16 * K2P) // 109568

__device__ __forceinline__ unsigned short f2bf(float f) {
    unsigned int u = __float_as_uint(f);
    u += 0x7FFFu + ((u >> 16) & 1u);    // RNE
    return (unsigned short)(u >> 16);
}

__device__ __forceinline__ unsigned int pkbf(float a, float b) {
    unsigned int r;
    asm("v_cvt_pk_bf16_f32 %0, %1, %2" : "=v"(r) : "v"(a), "v"(b));
    return r;   // [15:0]=bf16(a), [31:16]=bf16(b)
}

__device__ __forceinline__ bf16x8 cvt8(float4 a, float4 b) {
    union { unsigned int w[4]; bf16x8 v; } u;
    u.w[0] = pkbf(a.x, a.y);
    u.w[1] = pkbf(a.z, a.w);
    u.w[2] = pkbf(b.x, b.y);
    u.w[3] = pkbf(b.z, b.w);
    return u.v;
}

// ---------------- Kernel A: all weights -> bf16, transposed, padded
__global__ void build_weights(const float* __restrict__ w_conv,
                              const float* __restrict__ W1,
                              const float* __restrict__ W2,
                              const float* __restrict__ W3,
                              unsigned short* __restrict__ ws) {
    const int idx = blockIdx.x * 256 + threadIdx.x;
    if (idx >= WS_USHORTS) return;
    float v = 0.f;
    if (idx < W2T_OFF) {                       // weff_t[col][p]
        const int col = idx / KP1, p = idx % KP1;
        if (col < 100 && p < 784) {
            const int y = p / 28, xx = p % 28;
#pragma unroll
            for (int ky = 0; ky < 3; ++ky) {
                const int py = y - ky;
                if (py < 0 || py >= 26) continue;
#pragma unroll
                for (int kx = 0; kx < 3; ++kx) {
                    const int px = xx - kx;
                    if (px < 0 || px >= 26) continue;
                    v += w_conv[ky * 3 + kx] * W1[(py * 26 + px) * 100 + col];
                }
            }
        }
    } else if (idx < W3T_OFF) {                // w2t[col][k] = W2[k][col]
        const int r = idx - W2T_OFF;
        const int col = r / K2P, k = r % K2P;
        if (col < 100 && k < 100) v = W2[k * 100 + col];
    } else {                                   // w3t[col][k] = W3[k][col]
        const int r = idx - W3T_OFF;
        const int col = r / K2P, k = r % K2P;
        if (col < 10 && k < 100) v = W3[k * 10 + col];
    }
    ws[idx] = f2bf(v);
}

// ---------------- Kernel B: fused, barrier-free
__global__ __launch_bounds__(NT, 2)
void fused(const float* __restrict__ x,
           const unsigned short* __restrict__ wst,
           const float* __restrict__ b1,
           const float* __restrict__ b2,
           const float* __restrict__ b3,
           float* __restrict__ out) {
    __shared__ unsigned short h1[BM][136];
    __shared__ unsigned short h2[BM][136];

    const int tid  = threadIdx.x;
    const int lane = tid & 63;
    const int wv   = tid >> 6;       // 0..3, wave owns rows wv*32 .. wv*32+31
    const int l15  = lane & 15;
    const int lk   = lane >> 4;      // 0..3
    const int b0   = blockIdx.x * BM;
    const int wr   = wv * 32;

    const unsigned short* weff = wst;
    const unsigned short* w2t  = wst + W2T_OFF;
    const unsigned short* w3t  = wst + W3T_OFF;

    // zero the k-pad columns (100..135) of this wave's rows, both buffers
    for (int f = lane; f < 32 * 18; f += 64) {     // 18 u32 per row
        const int r = wr + f / 18, c = 100 + (f % 18) * 2;
        *reinterpret_cast<unsigned int*>(&h1[r][c]) = 0u;
        *reinterpret_cast<unsigned int*>(&h2[r][c]) = 0u;
    }

    // A-frag source rows for this lane (m = 0,1)
    const float* xr0 = x + (size_t)(b0 + wr + l15) * 784;
    const float* xr1 = x + (size_t)(b0 + wr + 16 + l15) * 784;

    f32x4 acc[2][7];
#pragma unroll
    for (int m = 0; m < 2; ++m)
#pragma unroll
        for (int n = 0; n < 7; ++n) acc[m][n] = (f32x4){0.f, 0.f, 0.f, 0.f};

    float4 A0[2][2][2], A1[2][2][2];   // [m][ks][half]

    auto loadA = [&](int kt, float4 (&dst)[2][2][2]) {
#pragma unroll
        for (int ks = 0; ks < 2; ++ks)
#pragma unroll
            for (int h = 0; h < 2; ++h) {
                const int k = kt * 64 + ks * 32 + lk * 8 + h * 4;
                if (k < 784) {
                    dst[0][ks][h] = *reinterpret_cast<const float4*>(xr0 + k);
                    dst[1][ks][h] = *reinterpret_cast<const float4*>(xr1 + k);
                } else {
                    dst[0][ks][h] = (float4){0.f, 0.f, 0.f, 0.f};
                    dst[1][ks][h] = (float4){0.f, 0.f, 0.f, 0.f};
                }
            }
    };

    auto stage = [&](int kt, float4 (&cur)[2][2][2]) {
#pragma unroll
        for (int ks = 0; ks < 2; ++ks) {
            const int kb = kt * 64 + ks * 32 + lk * 8;
            bf16x8 bfr[7];
#pragma unroll
            for (int n = 0; n < 7; ++n)
                bfr[n] = *reinterpret_cast<const bf16x8*>(
                    weff + (size_t)(n * 16 + l15) * KP1 + kb);
            const bf16x8 af0 = cvt8(cur[0][ks][0], cur[0][ks][1]);
            const bf16x8 af1 = cvt8(cur[1][ks][0], cur[1][ks][1]);
#pragma unroll
            for (int n = 0; n < 7; ++n) {
                acc[0][n] = __builtin_amdgcn_mfma_f32_16x16x32_bf16(af0, bfr[n], acc[0][n], 0, 0, 0);
                acc[1][n] = __builtin_amdgcn_mfma_f32_16x16x32_bf16(af1, bfr[n], acc[1][n], 0, 0, 0);
            }
        }
    };

    // ---- GEMM1: 13 stages, A double-buffered 1 ahead, no barriers
    loadA(0, A0);
#pragma unroll 1
    for (int t = 0; t < 6; ++t) {
        loadA(2 * t + 1, A1);
        stage(2 * t, A0);
        loadA(2 * t + 2, A0);
        stage(2 * t + 1, A1);
    }
    stage(12, A0);

    // ---- h1 = relu(acc + b1) -> LDS (own rows only)
    float bias[7];
#pragma unroll
    for (int n = 0; n < 7; ++n) {
        const int c = n * 16 + l15;
        bias[n] = (c < 100) ? b1[c] : 0.f;
    }
#pragma unroll
    for (int m = 0; m < 2; ++m)
#pragma unroll
        for (int n = 0; n < 7; ++n) {
            const int col = n * 16 + l15;
            if (col < 100)
#pragma unroll
                for (int q = 0; q < 4; ++q) {
                    const float v = fmaxf(acc[m][n][q] + bias[n], 0.f);
                    h1[wr + m * 16 + lk * 4 + q][col] = f2bf(v);
                }
        }
    __builtin_amdgcn_sched_barrier(0);   // keep ds_writes before GEMM2 ds_reads

    // ---- GEMM2: h2 = relu(h1 @ W2 + b2)
    f32x4 acc2[2][7];
#pragma unroll
    for (int m = 0; m < 2; ++m)
#pragma unroll
        for (int n = 0; n < 7; ++n) acc2[m][n] = (f32x4){0.f, 0.f, 0.f, 0.f};
#pragma unroll
    for (int ks = 0; ks < 4; ++ks) {
        const int kb = ks * 32 + lk * 8;
        bf16x8 af[2];
#pragma unroll
        for (int m = 0; m < 2; ++m)
            af[m] = *reinterpret_cast<const bf16x8*>(&h1[wr + m * 16 + l15][kb]);
#pragma unroll
        for (int n = 0; n < 7; ++n) {
            const bf16x8 bfr = *reinterpret_cast<const bf16x8*>(
                w2t + (size_t)(n * 16 + l15) * K2P + kb);
#pragma unroll
            for (int m = 0; m < 2; ++m)
                acc2[m][n] = __builtin_amdgcn_mfma_f32_16x16x32_bf16(af[m], bfr, acc2[m][n], 0, 0, 0);
        }
    }

#pragma unroll
    for (int n = 0; n < 7; ++n) {
        const int c = n * 16 + l15;
        bias[n] = (c < 100) ? b2[c] : 0.f;
    }
#pragma unroll
    for (int m = 0; m < 2; ++m)
#pragma unroll
        for (int n = 0; n < 7; ++n) {
            const int col = n * 16 + l15;
            if (col < 100)
#pragma unroll
                for (int q = 0; q < 4; ++q) {
                    const float v = fmaxf(acc2[m][n][q] + bias[n], 0.f);
                    h2[wr + m * 16 + lk * 4 + q][col] = f2bf(v);
                }
        }
    __builtin_amdgcn_sched_barrier(0);

    // ---- GEMM3: out = h2 @ W3 + b3
    f32x4 acc3[2];
#pragma unroll
    for (int m = 0; m < 2; ++m) acc3[m] = (f32x4){0.f, 0.f, 0.f, 0.f};
#pragma unroll
    for (int ks = 0; ks < 4; ++ks) {
        const int kb = ks * 32 + lk * 8;
        const bf16x8 bfr = *reinterpret_cast<const bf16x8*>(
            w3t + (size_t)l15 * K2P + kb);
#pragma unroll
        for (int m = 0; m < 2; ++m) {
            const bf16x8 af = *reinterpret_cast<const bf16x8*>(&h2[wr + m * 16 + l15][kb]);
            acc3[m] = __builtin_amdgcn_mfma_f32_16x16x32_bf16(af, bfr, acc3[m], 0, 0, 0);
        }
    }

    if (l15 < 10) {
        const float bb = b3[l15];
#pragma unroll
        for (int m = 0; m < 2; ++m)
#pragma unroll
            for (int q = 0; q < 4; ++q) {
                const int row = b0 + wr + m * 16 + lk * 4 + q;
                out[(size_t)row * 10 + l15] = acc3[m][q] + bb;
            }
    }
}

extern "C" void kernel_launch(void* const* d_in, const int* in_sizes, int n_in,
                              void* d_out, int out_size, void* d_ws, size_t ws_size,
                              hipStream_t stream) {
    const float* x      = (const float*)d_in[0];
    const float* w_conv = (const float*)d_in[1];
    const float* W1     = (const float*)d_in[2];
    const float* b1     = (const float*)d_in[3];
    const float* W2     = (const float*)d_in[4];
    const float* b2     = (const float*)d_in[5];
    const float* W3     = (const float*)d_in[6];
    const float* b3     = (const float*)d_in[7];
    float* out = (float*)d_out;
    unsigned short* ws = (unsigned short*)d_ws;   // 219,136 B used

    build_weights<<<(WS_USHORTS + 255) / 256, 256, 0, stream>>>(w_conv, W1, W2, W3, ws);
    fused<<<32768 / BM, NT, 0, stream>>>(x, ws, b1, b2, b3, out);
}